// Round 6
// baseline (234.531 us; speedup 1.0000x reference)
//
#include <hip/hip_runtime.h>

#define B_ 2
#define T_ 2048
#define C_ 2048
#define NH_ 16
#define NKV_ 4
#define HD_ 128
#define M_ 4096          // B*T
#define NQKV_ 3072       // C + 2*NKV*HD

typedef __bf16 bf16x8 __attribute__((ext_vector_type(8)));
typedef float f32x4 __attribute__((ext_vector_type(4)));
typedef float f32x16 __attribute__((ext_vector_type(16)));

__device__ __forceinline__ unsigned short f2bf(float f) {
  union { float f; unsigned u; } c{f};
  unsigned u = c.u + 0x7FFFu + ((c.u >> 16) & 1u);
  return (unsigned short)(u >> 16);
}
__device__ __forceinline__ float bf2f(unsigned short h) {
  union { unsigned u; float f; } c{(unsigned)h << 16};
  return c.f;
}

#define GLOAD_LDS16(g, l)                                        \
  __builtin_amdgcn_global_load_lds(                              \
      (const __attribute__((address_space(1))) void*)(g),        \
      (__attribute__((address_space(3))) void*)(l), 16, 0, 0)

// ---------------- RoPE cos/sin table: rt[t*64+i] = {cos,sin}(t * 10000^(-2i/128))
__global__ void rope_table_kernel(float2* __restrict__ rt) {
  int t = blockIdx.x, i = threadIdx.x;  // 2048 x 64
  float inv = powf(10000.f, -(float)(2 * i) / 128.f);
  float s, c;
  sincosf((float)t * inv, &s, &c);
  rt[t * 64 + i] = make_float2(c, s);
}

// ---------------- x f32 -> bf16 (vectorized)
__global__ void convx_kernel(const float* __restrict__ x, unsigned short* __restrict__ xb, int n4) {
  int i = blockIdx.x * blockDim.x + threadIdx.x;
  if (i >= n4) return;
  float4 v = reinterpret_cast<const float4*>(x)[i];
  union { ushort4 u; unsigned short s[4]; } o;
  o.s[0] = f2bf(v.x); o.s[1] = f2bf(v.y); o.s[2] = f2bf(v.z); o.s[3] = f2bf(v.w);
  reinterpret_cast<ushort4*>(xb)[i] = o.u;
}

// ---------------- all 4 weights (K x N, f32) -> Wt (N x K, bf16), one launch
__global__ void transpose_conv4_kernel(const float* __restrict__ Wq, const float* __restrict__ Wk,
                                       const float* __restrict__ Wv, const float* __restrict__ Wp,
                                       unsigned short* __restrict__ wt) {
  __shared__ float tile[32][33];
  int id = blockIdx.x;
  const float* W;
  unsigned short* Wt;
  int N, bx, by;
  if (id < 4096)      { W = Wq; Wt = wt;                          N = 2048; int u = id;        bx = u & 63; by = u >> 6; }
  else if (id < 5120) { W = Wk; Wt = wt + (size_t)2048 * 2048;    N = 512;  int u = id - 4096; bx = u & 15; by = u >> 4; }
  else if (id < 6144) { W = Wv; Wt = wt + (size_t)2560 * 2048;    N = 512;  int u = id - 5120; bx = u & 15; by = u >> 4; }
  else                { W = Wp; Wt = wt + (size_t)3072 * 2048;    N = 2048; int u = id - 6144; bx = u & 63; by = u >> 6; }
  const int K = 2048;
  bx *= 32; by *= 32;
  int tx = threadIdx.x & 31, ty = threadIdx.x >> 5;  // 32x8
#pragma unroll
  for (int r = 0; r < 32; r += 8)
    tile[ty + r][tx] = W[(size_t)(by + ty + r) * N + bx + tx];
  __syncthreads();
#pragma unroll
  for (int r = 0; r < 32; r += 8)
    Wt[(size_t)(bx + ty + r) * K + by + tx] = f2bf(tile[tx][ty + r]);
}

// ---------------- RoPE applied in-place to q (cols 0..2047) and k (cols 2048..2559)
__global__ void rope_kernel(unsigned short* __restrict__ qkv, const float2* __restrict__ rt) {
  int g = blockIdx.x * blockDim.x + threadIdx.x;
  if (g >= M_ * 160) return;          // 160 octet-pairs per row: 128 q + 32 k
  int m = g / 160, u = g - m * 160;
  int t = m & (T_ - 1);
  int io, col0;
  if (u < 128) { io = (u & 7) * 8; col0 = (u >> 3) * HD_ + io; }
  else         { int uu = u - 128; io = (uu & 7) * 8; col0 = C_ + (uu >> 3) * HD_ + io; }
  unsigned short* p = qkv + (size_t)m * NQKV_ + col0;
  union V8 { uint4 v; unsigned short s[8]; };
  V8 a, b, oa, ob;
  a.v = *reinterpret_cast<const uint4*>(p);
  b.v = *reinterpret_cast<const uint4*>(p + 64);
#pragma unroll
  for (int j = 0; j < 8; ++j) {
    float2 cs = rt[t * 64 + io + j];
    float x1 = bf2f(a.s[j]), x2 = bf2f(b.s[j]);
    oa.s[j] = f2bf(x1 * cs.x - x2 * cs.y);
    ob.s[j] = f2bf(x2 * cs.x + x1 * cs.y);
  }
  *reinterpret_cast<uint4*>(p) = oa.v;
  *reinterpret_cast<uint4*>(p + 64) = ob.v;
}

// ---------------- V slice of qkv -> vt[(b*NKV+kvh)*HD + d][t]  (bf16 transpose)
__global__ void transpose_v_kernel(const unsigned short* __restrict__ qkv,
                                   unsigned short* __restrict__ vt) {
  __shared__ unsigned short tile[32][33];
  int bh = blockIdx.z;                 // b*NKV + kvh
  int b = bh >> 2, kvh = bh & 3;
  int t0 = blockIdx.x * 32, d0 = blockIdx.y * 32;
  int tx = threadIdx.x & 31, ty = threadIdx.x >> 5;
#pragma unroll
  for (int r = 0; r < 32; r += 8)
    tile[ty + r][tx] = qkv[(size_t)(b * T_ + t0 + ty + r) * NQKV_ + 2560 + kvh * HD_ + d0 + tx];
  __syncthreads();
#pragma unroll
  for (int r = 0; r < 32; r += 8)
    vt[(size_t)(bh * HD_ + d0 + ty + r) * T_ + t0 + tx] = tile[tx][ty + r];
}

// ---------------- bf16 GEMM: C(MxN) = A(MxK) * Bt(NxK)^T, 128x128 tile, BK=32
template <typename OUT>
__global__ __launch_bounds__(256) void gemm_bf16(const unsigned short* __restrict__ A,
                                                 const unsigned short* __restrict__ Bt,
                                                 OUT* __restrict__ Cm,
                                                 int M, int N, int K) {
  constexpr int BK = 32;
  __shared__ __align__(16) unsigned short Al[2][128 * BK];
  __shared__ __align__(16) unsigned short Bl[2][128 * BK];
  int tid = threadIdx.x, w = tid >> 6, lane = tid & 63;
  int l15 = lane & 15, l4 = lane >> 4;
  int wr = w >> 1, wc = w & 1;  // wave -> 64x64 quadrant
  size_t arow0 = (size_t)blockIdx.y * 128;
  size_t brow0 = (size_t)blockIdx.x * 128;

  f32x4 acc[4][4];
#pragma unroll
  for (int mi = 0; mi < 4; ++mi)
#pragma unroll
    for (int ni = 0; ni < 4; ++ni) acc[mi][ni] = (f32x4){0.f, 0.f, 0.f, 0.f};

  auto stage = [&](int buf, int k0) {
#pragma unroll
    for (int i = 0; i < 2; ++i) {                 // A tile: 8KB = 8 wave-insts
      int c = i * 256 + w * 64 + lane;            // chunk 0..511 (16B each)
      const unsigned short* g = A + (arow0 + (c >> 2)) * K + k0 + (c & 3) * 8;
      GLOAD_LDS16(g, &Al[buf][(i * 4 + w) * 512]);
    }
#pragma unroll
    for (int i = 0; i < 2; ++i) {
      int c = i * 256 + w * 64 + lane;
      const unsigned short* g = Bt + (brow0 + (c >> 2)) * K + k0 + (c & 3) * 8;
      GLOAD_LDS16(g, &Bl[buf][(i * 4 + w) * 512]);
    }
  };

  stage(0, 0);
  __syncthreads();
  int NT = K / BK, cur = 0;
  for (int kt = 0; kt < NT; ++kt) {
    if (kt + 1 < NT) stage(cur ^ 1, (kt + 1) * BK);
    const unsigned short* Ab = &Al[cur][0];
    const unsigned short* Bb = &Bl[cur][0];
    bf16x8 af[4], bfr[4];
#pragma unroll
    for (int mi = 0; mi < 4; ++mi)
      af[mi] = *reinterpret_cast<const bf16x8*>(Ab + (wr * 64 + mi * 16 + l15) * BK + l4 * 8);
#pragma unroll
    for (int ni = 0; ni < 4; ++ni)
      bfr[ni] = *reinterpret_cast<const bf16x8*>(Bb + (wc * 64 + ni * 16 + l15) * BK + l4 * 8);
#pragma unroll
    for (int mi = 0; mi < 4; ++mi)
#pragma unroll
      for (int ni = 0; ni < 4; ++ni)
        acc[mi][ni] = __builtin_amdgcn_mfma_f32_16x16x32_bf16(af[mi], bfr[ni], acc[mi][ni], 0, 0, 0);
    __syncthreads();
    cur ^= 1;
  }

#pragma unroll
  for (int mi = 0; mi < 4; ++mi)
#pragma unroll
    for (int ni = 0; ni < 4; ++ni) {
      size_t row = arow0 + wr * 64 + mi * 16 + l4 * 4;
      size_t col = brow0 + wc * 64 + ni * 16 + l15;
#pragma unroll
      for (int r = 0; r < 4; ++r) {
        float v = acc[mi][ni][r];
        if constexpr (sizeof(OUT) == 4) Cm[(row + r) * N + col] = v;
        else                            Cm[(row + r) * N + col] = f2bf(v);
      }
    }
}

// ---------------- flash attention: QBLK=128 (4 waves x 32 q-rows), KVBLK=64, GQA
// 32x32 swapped QK^T, in-register softmax, P^T via xor-32 exchange.
// T3/T4: K 3-deep / V 2-deep pipeline with counted vmcnt (never drained to 0
// in the loop): per iter issue [V(t+1), K(t+2)]; vmcnt(16)+bar -> QK(t);
// vmcnt(12)+bar -> PV(t); bar. Constant issue counts via tail clamping.
__global__ __launch_bounds__(256, 2) void attn_kernel(const unsigned short* __restrict__ qkv,
                                                      const unsigned short* __restrict__ vt,
                                                      unsigned short* __restrict__ att) {
  constexpr int KB = 64;
  __shared__ __align__(16) unsigned short Kl[3][KB * 128];   // [kv][d] 48KB, swizzled
  __shared__ __align__(16) unsigned short Vl[2][128 * KB];   // [d][kv] 32KB, swizzled
  int tid = threadIdx.x, w = tid >> 6, lane = tid & 63;
  int l31 = lane & 31, hi = lane >> 5;
  int h4 = hi * 4;

  // balanced decode: ids k and k+256 get q-tiles summing to 15
  int id = blockIdx.x;
  int u = id & 255, half = id >> 8;
  int bh = u & 31;
  int qh = u >> 5;                       // 0..7
  int qi = half ? (15 - qh) : qh;        // 0..15
  int q0 = qi * 128;
  int b = bh >> 4, hd = bh & 15, kvh = hd >> 2;
  int qr0 = q0 + w * 32;   // this wave's first q row
  int ql = qr0 + l31;      // this lane's q row

  // Q^T B-fragments: lane holds Q[ql][df*16 + hi*8 + j], pre-scaled by 1/sqrt(HD)
  bf16x8 qf[8];
  {
    const unsigned short* qb = qkv + (size_t)(b * T_ + ql) * NQKV_ + hd * HD_ + hi * 8;
    const float scale = 0.08838834764831845f;
#pragma unroll
    for (int df = 0; df < 8; ++df) {
      bf16x8 t = *reinterpret_cast<const bf16x8*>(qb + df * 16);
#pragma unroll
      for (int j = 0; j < 8; ++j) t[j] = (__bf16)((float)t[j] * scale);
      qf[df] = t;
    }
  }

  f32x16 o[4];  // O^T accumulators: d = dt*32 + (r&3)+8*(r>>2)+h4, col q=l31
#pragma unroll
  for (int dt = 0; dt < 4; ++dt)
#pragma unroll
    for (int r = 0; r < 16; ++r) o[dt][r] = 0.f;
  float mr = -1e30f, lr = 0.f;

  int nt = q0 / KB + 2;  // causal: tiles up to q0+128

  auto stage_K = [&](int buf, int tile) {
    int kv0 = tile * KB;
#pragma unroll
    for (int i = 0; i < 4; ++i) {  // chunk c ^= (row&7), row = c>>4
      int c = (i * 4 + w) * 64 + lane;
      int g = c ^ ((c >> 4) & 7);
      const unsigned short* src =
          qkv + (size_t)(b * T_ + kv0 + (g >> 4)) * NQKV_ + C_ + kvh * HD_ + (g & 15) * 8;
      GLOAD_LDS16(src, &Kl[buf][(i * 4 + w) * 512]);
    }
  };
  auto stage_V = [&](int buf, int tile) {
    int kv0 = tile * KB;
#pragma unroll
    for (int i = 0; i < 4; ++i) {  // chunk c ^= (row&7), row = c>>3
      int c = (i * 4 + w) * 64 + lane;
      int g = c ^ ((c >> 3) & 7);
      const unsigned short* src =
          vt + (size_t)((b * NKV_ + kvh) * HD_ + (g >> 3)) * T_ + kv0 + (g & 7) * 8;
      GLOAD_LDS16(src, &Vl[buf][(i * 4 + w) * 512]);
    }
  };

  // prologue: K(0), V(0), K(1)   (order matters for the vmcnt algebra)
  stage_K(0, 0);
  stage_V(0, 0);
  stage_K(1, nt > 1 ? 1 : 0);

  for (int kt = 0; kt < nt; ++kt) {
    int kv0 = kt * KB;
    // issue V(t+1) then K(t+2), clamped so counts stay constant
    int tv = kt + 1 < nt ? kt + 1 : nt - 1;
    int tk = kt + 2 < nt ? kt + 2 : nt - 1;
    stage_V((kt + 1) & 1, tv);
    stage_K((kt + 2) % 3, tk);

    // wait K(t) landed (16 newest in flight: V(t),K(t+1),V(t+1),K(t+2))
    asm volatile("s_waitcnt vmcnt(16)" ::: "memory");
    __builtin_amdgcn_s_barrier();
    asm volatile("" ::: "memory");

    bool active = (kv0 <= qr0 + 31);
    f32x16 s[2];
    unsigned pk[2][8];
    if (active) {
      // S^T = K Q^T; lane: q=l31, k = t2*32 + (r&3)+8(r>>2)+h4
#pragma unroll
      for (int r = 0; r < 16; ++r) { s[0][r] = 0.f; s[1][r] = 0.f; }
      const unsigned short* Kb = &Kl[kt % 3][0];
      __builtin_amdgcn_s_setprio(1);
#pragma unroll
      for (int t2 = 0; t2 < 2; ++t2)
#pragma unroll
        for (int df = 0; df < 8; ++df) {
          bf16x8 kf = *reinterpret_cast<const bf16x8*>(
              Kb + (((t2 * 32 + l31) * 128 + df * 16 + hi * 8) ^ ((l31 & 7) << 3)));
          s[t2] = __builtin_amdgcn_mfma_f32_32x32x16_bf16(kf, qf[df], s[t2], 0, 0, 0);
        }
      __builtin_amdgcn_s_setprio(0);

      // mask + row-max (in-lane + one cross-half shfl)
      bool need_mask = (kv0 + KB - 1) > qr0;
      float rm = -1e30f;
#pragma unroll
      for (int t2 = 0; t2 < 2; ++t2)
#pragma unroll
        for (int r = 0; r < 16; ++r) {
          float sv = s[t2][r];
          int kcol = kv0 + t2 * 32 + (r & 3) + 8 * (r >> 2) + h4;
          if (need_mask && kcol > ql) sv = -1e30f;
          s[t2][r] = sv;
          rm = fmaxf(rm, sv);
        }
      rm = fmaxf(rm, __shfl_xor(rm, 32));

      // defer-max (THR=8)
      if (!__all(rm <= mr + 8.f)) {
        float mnew = fmaxf(mr, rm);
        float alpha = __expf(mr - mnew);
        mr = mnew;
        lr *= alpha;
#pragma unroll
        for (int dt = 0; dt < 4; ++dt)
#pragma unroll
          for (int r = 0; r < 16; ++r) o[dt][r] *= alpha;
      }

      // exp + per-lane partial sum (cross-half reduce deferred to epilogue)
      float ps = 0.f;
#pragma unroll
      for (int t2 = 0; t2 < 2; ++t2)
#pragma unroll
        for (int r = 0; r < 16; ++r) {
          float p = __expf(s[t2][r] - mr);
          s[t2][r] = p;
          ps += p;
        }
      lr += ps;

      // pack P to bf16 pairs
#pragma unroll
      for (int t2 = 0; t2 < 2; ++t2)
#pragma unroll
        for (int i = 0; i < 8; ++i) {
          union { unsigned u32; __bf16 hh[2]; } pr;
          pr.hh[0] = (__bf16)s[t2][2 * i];
          pr.hh[1] = (__bf16)s[t2][2 * i + 1];
          pk[t2][i] = pr.u32;
        }
    }

    // wait V(t) landed (12 newest in flight: K(t+1),V(t+1),K(t+2))
    asm volatile("s_waitcnt vmcnt(12)" ::: "memory");
    __builtin_amdgcn_s_barrier();
    asm volatile("" ::: "memory");

    if (active) {
      // assemble P^T B-frags via xor-32 exchange
      bf16x8 pb[4];
#pragma unroll
      for (int f = 0; f < 4; ++f) {
        int t2 = f >> 1, bq = (f & 1) * 4;
        union { bf16x8 v; unsigned d[4]; } fr;
#pragma unroll
        for (int p = 0; p < 2; ++p) {
          unsigned uu = pk[t2][bq + p];          // consumed by hi=0 lanes
          unsigned ww = pk[t2][bq + 2 + p];      // consumed by hi=1 lanes
          unsigned us = (unsigned)__shfl_xor((int)uu, 32);
          unsigned ws = (unsigned)__shfl_xor((int)ww, 32);
          fr.d[p]     = hi ? ws : uu;
          fr.d[2 + p] = hi ? ww : us;
        }
        pb[f] = fr.v;
      }

      // O^T += V^T P^T
      const unsigned short* Vb = &Vl[kt & 1][0];
      __builtin_amdgcn_s_setprio(1);
#pragma unroll
      for (int dt = 0; dt < 4; ++dt)
#pragma unroll
        for (int kf = 0; kf < 4; ++kf) {
          bf16x8 vf = *reinterpret_cast<const bf16x8*>(
              Vb + (((dt * 32 + l31) * KB + kf * 16 + hi * 8) ^ ((l31 & 7) << 3)));
          o[dt] = __builtin_amdgcn_mfma_f32_32x32x16_bf16(vf, pb[kf], o[dt], 0, 0, 0);
        }
      __builtin_amdgcn_s_setprio(0);
    }

    // protect Kl[(t+3)%3]=Kl[t%3] and Vl[(t+2)&1]=Vl[t&1] from next iter's stage
    __builtin_amdgcn_s_barrier();
    asm volatile("" ::: "memory");
  }

  // epilogue: finish l reduce, normalize, scatter O^T back to att[q][d]
  float ls = lr + __shfl_xor(lr, 32);
  float inv = 1.f / ls;
  unsigned short* ob = att + (size_t)(b * T_ + ql) * C_ + hd * HD_;
#pragma unroll
  for (int dt = 0; dt < 4; ++dt)
#pragma unroll
    for (int r = 0; r < 16; ++r) {
      int d = dt * 32 + (r & 3) + 8 * (r >> 2) + h4;
      ob[d] = f2bf(o[dt][r] * inv);
    }
}

extern "C" void kernel_launch(void* const* d_in, const int* in_sizes, int n_in,
                              void* d_out, int out_size, void* d_ws, size_t ws_size,
                              hipStream_t stream) {
  const float* x  = (const float*)d_in[0];
  const float* Wq = (const float*)d_in[1];
  const float* Wk = (const float*)d_in[2];
  const float* Wv = (const float*)d_in[3];
  const float* Wp = (const float*)d_in[4];
  float* out = (float*)d_out;
  char* ws = (char*)d_ws;

  // workspace layout (bytes); total 68,157,440
  unsigned short* xb  = (unsigned short*)(ws);              // 4096x2048 bf16 (reused as att)
  unsigned short* wt  = (unsigned short*)(ws + 16777216);   // 5120x2048 bf16 (Wq^T|Wk^T|Wv^T|Wp^T)
  unsigned short* qkv = (unsigned short*)(ws + 37748736);   // 4096x3072 bf16
  float2*         rt  = (float2*)(ws + 62914560);           // 2048x64 {cos,sin}
  unsigned short* vt  = (unsigned short*)(ws + 63963136);   // 8x128x2048 bf16
  unsigned short* att = xb;                                 // alias: xb dead after GEMM1

  rope_table_kernel<<<T_, 64, 0, stream>>>(rt);
  convx_kernel<<<(M_ * C_ / 4 + 255) / 256, 256, 0, stream>>>(x, xb, M_ * C_ / 4);
  transpose_conv4_kernel<<<dim3(10240), 256, 0, stream>>>(Wq, Wk, Wv, Wp, wt);

  gemm_bf16<unsigned short><<<dim3(NQKV_ / 128, M_ / 128), 256, 0, stream>>>(
      xb, wt, qkv, M_, NQKV_, C_);
  rope_kernel<<<(M_ * 160 + 255) / 256, 256, 0, stream>>>(qkv, rt);
  transpose_v_kernel<<<dim3(T_ / 32, HD_ / 32, B_ * NKV_), 256, 0, stream>>>(qkv, vt);
  attn_kernel<<<dim3(512), 256, 0, stream>>>(qkv, vt, att);
  gemm_bf16<float><<<dim3(C_ / 128, M_ / 128), 256, 0, stream>>>(
      att, wt + (size_t)3072 * 2048, out, M_, C_, C_);
}

// Round 7
// 232.140 us; speedup vs baseline: 1.0103x; 1.0103x over previous
//
#include <hip/hip_runtime.h>

#define B_ 2
#define T_ 2048
#define C_ 2048
#define NH_ 16
#define NKV_ 4
#define HD_ 128
#define M_ 4096          // B*T
#define NQKV_ 3072       // C + 2*NKV*HD

typedef __bf16 bf16x8 __attribute__((ext_vector_type(8)));
typedef float f32x4 __attribute__((ext_vector_type(4)));
typedef float f32x16 __attribute__((ext_vector_type(16)));

__device__ __forceinline__ unsigned short f2bf(float f) {
  union { float f; unsigned u; } c{f};
  unsigned u = c.u + 0x7FFFu + ((c.u >> 16) & 1u);
  return (unsigned short)(u >> 16);
}
__device__ __forceinline__ float bf2f(unsigned short h) {
  union { unsigned u; float f; } c{(unsigned)h << 16};
  return c.f;
}

#define GLOAD_LDS16(g, l)                                        \
  __builtin_amdgcn_global_load_lds(                              \
      (const __attribute__((address_space(1))) void*)(g),        \
      (__attribute__((address_space(3))) void*)(l), 16, 0, 0)

// ---------------- RoPE cos/sin table: rt[t*64+i] = {cos,sin}(t * 10000^(-2i/128))
__global__ void rope_table_kernel(float2* __restrict__ rt) {
  int t = blockIdx.x, i = threadIdx.x;  // 2048 x 64
  float inv = powf(10000.f, -(float)(2 * i) / 128.f);
  float s, c;
  sincosf((float)t * inv, &s, &c);
  rt[t * 64 + i] = make_float2(c, s);
}

// ---------------- x f32 -> bf16 (vectorized)
__global__ void convx_kernel(const float* __restrict__ x, unsigned short* __restrict__ xb, int n4) {
  int i = blockIdx.x * blockDim.x + threadIdx.x;
  if (i >= n4) return;
  float4 v = reinterpret_cast<const float4*>(x)[i];
  union { ushort4 u; unsigned short s[4]; } o;
  o.s[0] = f2bf(v.x); o.s[1] = f2bf(v.y); o.s[2] = f2bf(v.z); o.s[3] = f2bf(v.w);
  reinterpret_cast<ushort4*>(xb)[i] = o.u;
}

// ---------------- all 4 weights (K x N, f32) -> Wt (N x K, bf16), one launch
__global__ void transpose_conv4_kernel(const float* __restrict__ Wq, const float* __restrict__ Wk,
                                       const float* __restrict__ Wv, const float* __restrict__ Wp,
                                       unsigned short* __restrict__ wt) {
  __shared__ float tile[32][33];
  int id = blockIdx.x;
  const float* W;
  unsigned short* Wt;
  int N, bx, by;
  if (id < 4096)      { W = Wq; Wt = wt;                          N = 2048; int u = id;        bx = u & 63; by = u >> 6; }
  else if (id < 5120) { W = Wk; Wt = wt + (size_t)2048 * 2048;    N = 512;  int u = id - 4096; bx = u & 15; by = u >> 4; }
  else if (id < 6144) { W = Wv; Wt = wt + (size_t)2560 * 2048;    N = 512;  int u = id - 5120; bx = u & 15; by = u >> 4; }
  else                { W = Wp; Wt = wt + (size_t)3072 * 2048;    N = 2048; int u = id - 6144; bx = u & 63; by = u >> 6; }
  const int K = 2048;
  bx *= 32; by *= 32;
  int tx = threadIdx.x & 31, ty = threadIdx.x >> 5;  // 32x8
#pragma unroll
  for (int r = 0; r < 32; r += 8)
    tile[ty + r][tx] = W[(size_t)(by + ty + r) * N + bx + tx];
  __syncthreads();
#pragma unroll
  for (int r = 0; r < 32; r += 8)
    Wt[(size_t)(bx + ty + r) * K + by + tx] = f2bf(tile[tx][ty + r]);
}

// ---------------- RoPE applied in-place to q (cols 0..2047) and k (cols 2048..2559)
__global__ void rope_kernel(unsigned short* __restrict__ qkv, const float2* __restrict__ rt) {
  int g = blockIdx.x * blockDim.x + threadIdx.x;
  if (g >= M_ * 160) return;          // 160 octet-pairs per row: 128 q + 32 k
  int m = g / 160, u = g - m * 160;
  int t = m & (T_ - 1);
  int io, col0;
  if (u < 128) { io = (u & 7) * 8; col0 = (u >> 3) * HD_ + io; }
  else         { int uu = u - 128; io = (uu & 7) * 8; col0 = C_ + (uu >> 3) * HD_ + io; }
  unsigned short* p = qkv + (size_t)m * NQKV_ + col0;
  union V8 { uint4 v; unsigned short s[8]; };
  V8 a, b, oa, ob;
  a.v = *reinterpret_cast<const uint4*>(p);
  b.v = *reinterpret_cast<const uint4*>(p + 64);
#pragma unroll
  for (int j = 0; j < 8; ++j) {
    float2 cs = rt[t * 64 + io + j];
    float x1 = bf2f(a.s[j]), x2 = bf2f(b.s[j]);
    oa.s[j] = f2bf(x1 * cs.x - x2 * cs.y);
    ob.s[j] = f2bf(x2 * cs.x + x1 * cs.y);
  }
  *reinterpret_cast<uint4*>(p) = oa.v;
  *reinterpret_cast<uint4*>(p + 64) = ob.v;
}

// ---------------- V slice of qkv -> vt[(b*NKV+kvh)*HD + d][t]  (bf16 transpose)
__global__ void transpose_v_kernel(const unsigned short* __restrict__ qkv,
                                   unsigned short* __restrict__ vt) {
  __shared__ unsigned short tile[32][33];
  int bh = blockIdx.z;                 // b*NKV + kvh
  int b = bh >> 2, kvh = bh & 3;
  int t0 = blockIdx.x * 32, d0 = blockIdx.y * 32;
  int tx = threadIdx.x & 31, ty = threadIdx.x >> 5;
#pragma unroll
  for (int r = 0; r < 32; r += 8)
    tile[ty + r][tx] = qkv[(size_t)(b * T_ + t0 + ty + r) * NQKV_ + 2560 + kvh * HD_ + d0 + tx];
  __syncthreads();
#pragma unroll
  for (int r = 0; r < 32; r += 8)
    vt[(size_t)(bh * HD_ + d0 + ty + r) * T_ + t0 + tx] = tile[tx][ty + r];
}

// ---------------- bf16 GEMM: C(MxN) = A(MxK) * Bt(NxK)^T, 128x128 tile, BK=32
template <typename OUT>
__global__ __launch_bounds__(256) void gemm_bf16(const unsigned short* __restrict__ A,
                                                 const unsigned short* __restrict__ Bt,
                                                 OUT* __restrict__ Cm,
                                                 int M, int N, int K) {
  constexpr int BK = 32;
  __shared__ __align__(16) unsigned short Al[2][128 * BK];
  __shared__ __align__(16) unsigned short Bl[2][128 * BK];
  int tid = threadIdx.x, w = tid >> 6, lane = tid & 63;
  int l15 = lane & 15, l4 = lane >> 4;
  int wr = w >> 1, wc = w & 1;  // wave -> 64x64 quadrant
  size_t arow0 = (size_t)blockIdx.y * 128;
  size_t brow0 = (size_t)blockIdx.x * 128;

  f32x4 acc[4][4];
#pragma unroll
  for (int mi = 0; mi < 4; ++mi)
#pragma unroll
    for (int ni = 0; ni < 4; ++ni) acc[mi][ni] = (f32x4){0.f, 0.f, 0.f, 0.f};

  auto stage = [&](int buf, int k0) {
#pragma unroll
    for (int i = 0; i < 2; ++i) {                 // A tile: 8KB = 8 wave-insts
      int c = i * 256 + w * 64 + lane;            // chunk 0..511 (16B each)
      const unsigned short* g = A + (arow0 + (c >> 2)) * K + k0 + (c & 3) * 8;
      GLOAD_LDS16(g, &Al[buf][(i * 4 + w) * 512]);
    }
#pragma unroll
    for (int i = 0; i < 2; ++i) {
      int c = i * 256 + w * 64 + lane;
      const unsigned short* g = Bt + (brow0 + (c >> 2)) * K + k0 + (c & 3) * 8;
      GLOAD_LDS16(g, &Bl[buf][(i * 4 + w) * 512]);
    }
  };

  stage(0, 0);
  __syncthreads();
  int NT = K / BK, cur = 0;
  for (int kt = 0; kt < NT; ++kt) {
    if (kt + 1 < NT) stage(cur ^ 1, (kt + 1) * BK);
    const unsigned short* Ab = &Al[cur][0];
    const unsigned short* Bb = &Bl[cur][0];
    bf16x8 af[4], bfr[4];
#pragma unroll
    for (int mi = 0; mi < 4; ++mi)
      af[mi] = *reinterpret_cast<const bf16x8*>(Ab + (wr * 64 + mi * 16 + l15) * BK + l4 * 8);
#pragma unroll
    for (int ni = 0; ni < 4; ++ni)
      bfr[ni] = *reinterpret_cast<const bf16x8*>(Bb + (wc * 64 + ni * 16 + l15) * BK + l4 * 8);
#pragma unroll
    for (int mi = 0; mi < 4; ++mi)
#pragma unroll
      for (int ni = 0; ni < 4; ++ni)
        acc[mi][ni] = __builtin_amdgcn_mfma_f32_16x16x32_bf16(af[mi], bfr[ni], acc[mi][ni], 0, 0, 0);
    __syncthreads();
    cur ^= 1;
  }

#pragma unroll
  for (int mi = 0; mi < 4; ++mi)
#pragma unroll
    for (int ni = 0; ni < 4; ++ni) {
      size_t row = arow0 + wr * 64 + mi * 16 + l4 * 4;
      size_t col = brow0 + wc * 64 + ni * 16 + l15;
#pragma unroll
      for (int r = 0; r < 4; ++r) {
        float v = acc[mi][ni][r];
        if constexpr (sizeof(OUT) == 4) Cm[(row + r) * N + col] = v;
        else                            Cm[(row + r) * N + col] = f2bf(v);
      }
    }
}

// ---------------- flash attention: QBLK=128 (4 waves x 32 q-rows), KVBLK=64, GQA
// 32x32 swapped QK^T, in-register softmax, P^T via xor-32 exchange.
// T3/T4 rev2: K 3-buf (2 tiles ahead), V 2-buf (1 ahead); per iter exactly TWO
// barriers with split counted waits: vmcnt(8)+bar -> QK(t); vmcnt(4)+bar ->
// PV(t); then issue V(t+1),K(t+2) (tail-clamped so counts stay constant).
// vmcnt never drains to 0 inside the loop.
__global__ __launch_bounds__(256, 2) void attn_kernel(const unsigned short* __restrict__ qkv,
                                                      const unsigned short* __restrict__ vt,
                                                      unsigned short* __restrict__ att) {
  constexpr int KB = 64;
  __shared__ __align__(16) unsigned short Kl[3][KB * 128];   // [kv][d] 48KB, swizzled
  __shared__ __align__(16) unsigned short Vl[2][128 * KB];   // [d][kv] 32KB, swizzled
  int tid = threadIdx.x, w = tid >> 6, lane = tid & 63;
  int l31 = lane & 31, hi = lane >> 5;
  int h4 = hi * 4;

  // balanced decode: ids k and k+256 get q-tiles summing to 15
  int id = blockIdx.x;
  int u = id & 255, half = id >> 8;
  int bh = u & 31;
  int qh = u >> 5;                       // 0..7
  int qi = half ? (15 - qh) : qh;        // 0..15
  int q0 = qi * 128;
  int b = bh >> 4, hd = bh & 15, kvh = hd >> 2;
  int qr0 = q0 + w * 32;   // this wave's first q row
  int ql = qr0 + l31;      // this lane's q row

  // Q^T B-fragments: lane holds Q[ql][df*16 + hi*8 + j], pre-scaled by 1/sqrt(HD)
  bf16x8 qf[8];
  {
    const unsigned short* qb = qkv + (size_t)(b * T_ + ql) * NQKV_ + hd * HD_ + hi * 8;
    const float scale = 0.08838834764831845f;
#pragma unroll
    for (int df = 0; df < 8; ++df) {
      bf16x8 t = *reinterpret_cast<const bf16x8*>(qb + df * 16);
#pragma unroll
      for (int j = 0; j < 8; ++j) t[j] = (__bf16)((float)t[j] * scale);
      qf[df] = t;
    }
  }

  f32x16 o[4];  // O^T accumulators: d = dt*32 + (r&3)+8*(r>>2)+h4, col q=l31
#pragma unroll
  for (int dt = 0; dt < 4; ++dt)
#pragma unroll
    for (int r = 0; r < 16; ++r) o[dt][r] = 0.f;
  float mr = -1e30f, lr = 0.f;

  int nt = q0 / KB + 2;  // causal: tiles up to q0+128

  auto stage_K = [&](int buf, int tile) {
    int kv0 = tile * KB;
#pragma unroll
    for (int i = 0; i < 4; ++i) {  // chunk c ^= (row&7), row = c>>4
      int c = (i * 4 + w) * 64 + lane;
      int g = c ^ ((c >> 4) & 7);
      const unsigned short* src =
          qkv + (size_t)(b * T_ + kv0 + (g >> 4)) * NQKV_ + C_ + kvh * HD_ + (g & 15) * 8;
      GLOAD_LDS16(src, &Kl[buf][(i * 4 + w) * 512]);
    }
  };
  auto stage_V = [&](int buf, int tile) {
    int kv0 = tile * KB;
#pragma unroll
    for (int i = 0; i < 4; ++i) {  // chunk c ^= (row&7), row = c>>3
      int c = (i * 4 + w) * 64 + lane;
      int g = c ^ ((c >> 3) & 7);
      const unsigned short* src =
          vt + (size_t)((b * NKV_ + kvh) * HD_ + (g >> 3)) * T_ + kv0 + (g & 7) * 8;
      GLOAD_LDS16(src, &Vl[buf][(i * 4 + w) * 512]);
    }
  };

  // prologue: K(0), V(0), K(1)  — issue order is load-bearing for the vmcnt algebra
  stage_K(0, 0);
  stage_V(0, 0);
  stage_K(1, nt > 1 ? 1 : 0);

  for (int kt = 0; kt < nt; ++kt) {
    int kv0 = kt * KB;

    // K(t) landed for ALL waves (leaves V(t), K(t+1) = 8 loads in flight)
    asm volatile("s_waitcnt vmcnt(8)" ::: "memory");
    __builtin_amdgcn_s_barrier();
    __builtin_amdgcn_sched_barrier(0);

    bool active = (kv0 <= qr0 + 31);
    unsigned pk[2][8];
    if (active) {
      // S^T = K Q^T; lane: q=l31, k = t2*32 + (r&3)+8(r>>2)+h4
      f32x16 s[2];
#pragma unroll
      for (int r = 0; r < 16; ++r) { s[0][r] = 0.f; s[1][r] = 0.f; }
      const unsigned short* Kb = &Kl[kt % 3][0];
      __builtin_amdgcn_s_setprio(1);
#pragma unroll
      for (int t2 = 0; t2 < 2; ++t2)
#pragma unroll
        for (int df = 0; df < 8; ++df) {
          bf16x8 kf = *reinterpret_cast<const bf16x8*>(
              Kb + (((t2 * 32 + l31) * 128 + df * 16 + hi * 8) ^ ((l31 & 7) << 3)));
          s[t2] = __builtin_amdgcn_mfma_f32_32x32x16_bf16(kf, qf[df], s[t2], 0, 0, 0);
        }
      __builtin_amdgcn_s_setprio(0);

      // mask + row-max (in-lane + one cross-half shfl)
      bool need_mask = (kv0 + KB - 1) > qr0;
      float rm = -1e30f;
#pragma unroll
      for (int t2 = 0; t2 < 2; ++t2)
#pragma unroll
        for (int r = 0; r < 16; ++r) {
          float sv = s[t2][r];
          int kcol = kv0 + t2 * 32 + (r & 3) + 8 * (r >> 2) + h4;
          if (need_mask && kcol > ql) sv = -1e30f;
          s[t2][r] = sv;
          rm = fmaxf(rm, sv);
        }
      rm = fmaxf(rm, __shfl_xor(rm, 32));

      // defer-max (THR=8)
      if (!__all(rm <= mr + 8.f)) {
        float mnew = fmaxf(mr, rm);
        float alpha = __expf(mr - mnew);
        mr = mnew;
        lr *= alpha;
#pragma unroll
        for (int dt = 0; dt < 4; ++dt)
#pragma unroll
          for (int r = 0; r < 16; ++r) o[dt][r] *= alpha;
      }

      // exp + per-lane partial sum (cross-half reduce deferred to epilogue)
      float ps = 0.f;
#pragma unroll
      for (int t2 = 0; t2 < 2; ++t2)
#pragma unroll
        for (int r = 0; r < 16; ++r) {
          float p = __expf(s[t2][r] - mr);
          s[t2][r] = p;
          ps += p;
        }
      lr += ps;

      // pack P to bf16 pairs
#pragma unroll
      for (int t2 = 0; t2 < 2; ++t2)
#pragma unroll
        for (int i = 0; i < 8; ++i) {
          union { unsigned u32; __bf16 hh[2]; } pr;
          pr.hh[0] = (__bf16)s[t2][2 * i];
          pr.hh[1] = (__bf16)s[t2][2 * i + 1];
          pk[t2][i] = pr.u32;
        }
    }

    // V(t) landed for ALL waves (leaves K(t+1) = 4 loads in flight)
    asm volatile("s_waitcnt vmcnt(4)" ::: "memory");
    __builtin_amdgcn_s_barrier();
    __builtin_amdgcn_sched_barrier(0);

    if (active) {
      // assemble P^T B-frags via xor-32 exchange
      bf16x8 pb[4];
#pragma unroll
      for (int f = 0; f < 4; ++f) {
        int t2 = f >> 1, bq = (f & 1) * 4;
        union { bf16x8 v; unsigned d[4]; } fr;
#pragma unroll
        for (int p = 0; p < 2; ++p) {
          unsigned uu = pk[t2][bq + p];          // consumed by hi=0 lanes
          unsigned ww = pk[t2][bq + 2 + p];      // consumed by hi=1 lanes
          unsigned us = (unsigned)__shfl_xor((int)uu, 32);
          unsigned ws = (unsigned)__shfl_xor((int)ww, 32);
          fr.d[p]     = hi ? ws : uu;
          fr.d[2 + p] = hi ? ww : us;
        }
        pb[f] = fr.v;
      }

      // O^T += V^T P^T
      const unsigned short* Vb = &Vl[kt & 1][0];
      __builtin_amdgcn_s_setprio(1);
#pragma unroll
      for (int dt = 0; dt < 4; ++dt)
#pragma unroll
        for (int kf = 0; kf < 4; ++kf) {
          bf16x8 vf = *reinterpret_cast<const bf16x8*>(
              Vb + (((dt * 32 + l31) * KB + kf * 16 + hi * 8) ^ ((l31 & 7) << 3)));
          o[dt] = __builtin_amdgcn_mfma_f32_32x32x16_bf16(vf, pb[kf], o[dt], 0, 0, 0);
        }
      __builtin_amdgcn_s_setprio(0);
    }

    // issue next tiles (tail-clamped; dup loads are L2-hot and harmless).
    // Safety: V[(kt+1)&1] last read at PV(kt-1), K[(kt+2)%3] last read at
    // QK(kt-1) — all waves passed this iter's barriers, so both are dead.
    int tv = kt + 1 < nt ? kt + 1 : nt - 1;
    int tk = kt + 2 < nt ? kt + 2 : nt - 1;
    stage_V((kt + 1) & 1, tv);
    stage_K((kt + 2) % 3, tk);
  }

  // epilogue: finish l reduce, normalize, scatter O^T back to att[q][d]
  float ls = lr + __shfl_xor(lr, 32);
  float inv = 1.f / ls;
  unsigned short* ob = att + (size_t)(b * T_ + ql) * C_ + hd * HD_;
#pragma unroll
  for (int dt = 0; dt < 4; ++dt)
#pragma unroll
    for (int r = 0; r < 16; ++r) {
      int d = dt * 32 + (r & 3) + 8 * (r >> 2) + h4;
      ob[d] = f2bf(o[dt][r] * inv);
    }
}

extern "C" void kernel_launch(void* const* d_in, const int* in_sizes, int n_in,
                              void* d_out, int out_size, void* d_ws, size_t ws_size,
                              hipStream_t stream) {
  const float* x  = (const float*)d_in[0];
  const float* Wq = (const float*)d_in[1];
  const float* Wk = (const float*)d_in[2];
  const float* Wv = (const float*)d_in[3];
  const float* Wp = (const float*)d_in[4];
  float* out = (float*)d_out;
  char* ws = (char*)d_ws;

  // workspace layout (bytes); total 68,157,440
  unsigned short* xb  = (unsigned short*)(ws);              // 4096x2048 bf16 (reused as att)
  unsigned short* wt  = (unsigned short*)(ws + 16777216);   // 5120x2048 bf16 (Wq^T|Wk^T|Wv^T|Wp^T)
  unsigned short* qkv = (unsigned short*)(ws + 37748736);   // 4096x3072 bf16
  float2*         rt  = (float2*)(ws + 62914560);           // 2048x64 {cos,sin}
  unsigned short* vt  = (unsigned short*)(ws + 63963136);   // 8x128x2048 bf16
  unsigned short* att = xb;                                 // alias: xb dead after GEMM1

  rope_table_kernel<<<T_, 64, 0, stream>>>(rt);
  convx_kernel<<<(M_ * C_ / 4 + 255) / 256, 256, 0, stream>>>(x, xb, M_ * C_ / 4);
  transpose_conv4_kernel<<<dim3(10240), 256, 0, stream>>>(Wq, Wk, Wv, Wp, wt);

  gemm_bf16<unsigned short><<<dim3(NQKV_ / 128, M_ / 128), 256, 0, stream>>>(
      xb, wt, qkv, M_, NQKV_, C_);
  rope_kernel<<<(M_ * 160 + 255) / 256, 256, 0, stream>>>(qkv, rt);
  transpose_v_kernel<<<dim3(T_ / 32, HD_ / 32, B_ * NKV_), 256, 0, stream>>>(qkv, vt);
  attn_kernel<<<dim3(512), 256, 0, stream>>>(qkv, vt, att);
  gemm_bf16<float><<<dim3(C_ / 128, M_ / 128), 256, 0, stream>>>(
      att, wt + (size_t)3072 * 2048, out, M_, C_, C_);
}

// Round 8
// 220.230 us; speedup vs baseline: 1.0649x; 1.0541x over previous
//
#include <hip/hip_runtime.h>

#define B_ 2
#define T_ 2048
#define C_ 2048
#define NH_ 16
#define NKV_ 4
#define HD_ 128
#define M_ 4096          // B*T
#define NQKV_ 3072       // C + 2*NKV*HD

typedef __bf16 bf16x8 __attribute__((ext_vector_type(8)));
typedef float f32x4 __attribute__((ext_vector_type(4)));
typedef float f32x16 __attribute__((ext_vector_type(16)));

__device__ __forceinline__ unsigned short f2bf(float f) {
  union { float f; unsigned u; } c{f};
  unsigned u = c.u + 0x7FFFu + ((c.u >> 16) & 1u);
  return (unsigned short)(u >> 16);
}
__device__ __forceinline__ float bf2f(unsigned short h) {
  union { unsigned u; float f; } c{(unsigned)h << 16};
  return c.f;
}

#define GLOAD_LDS16(g, l)                                        \
  __builtin_amdgcn_global_load_lds(                              \
      (const __attribute__((address_space(1))) void*)(g),        \
      (__attribute__((address_space(3))) void*)(l), 16, 0, 0)

// ---------------- RoPE cos/sin table: rt[t*64+i] = {cos,sin}(t * 10000^(-2i/128))
__global__ void rope_table_kernel(float2* __restrict__ rt) {
  int t = blockIdx.x, i = threadIdx.x;  // 2048 x 64
  float inv = powf(10000.f, -(float)(2 * i) / 128.f);
  float s, c;
  sincosf((float)t * inv, &s, &c);
  rt[t * 64 + i] = make_float2(c, s);
}

// ---------------- x f32 -> bf16 (vectorized)
__global__ void convx_kernel(const float* __restrict__ x, unsigned short* __restrict__ xb, int n4) {
  int i = blockIdx.x * blockDim.x + threadIdx.x;
  if (i >= n4) return;
  float4 v = reinterpret_cast<const float4*>(x)[i];
  union { ushort4 u; unsigned short s[4]; } o;
  o.s[0] = f2bf(v.x); o.s[1] = f2bf(v.y); o.s[2] = f2bf(v.z); o.s[3] = f2bf(v.w);
  reinterpret_cast<ushort4*>(xb)[i] = o.u;
}

// ---------------- all 4 weights (K x N, f32) -> Wt (N x K, bf16), one launch
__global__ void transpose_conv4_kernel(const float* __restrict__ Wq, const float* __restrict__ Wk,
                                       const float* __restrict__ Wv, const float* __restrict__ Wp,
                                       unsigned short* __restrict__ wt) {
  __shared__ float tile[32][33];
  int id = blockIdx.x;
  const float* W;
  unsigned short* Wt;
  int N, bx, by;
  if (id < 4096)      { W = Wq; Wt = wt;                          N = 2048; int u = id;        bx = u & 63; by = u >> 6; }
  else if (id < 5120) { W = Wk; Wt = wt + (size_t)2048 * 2048;    N = 512;  int u = id - 4096; bx = u & 15; by = u >> 4; }
  else if (id < 6144) { W = Wv; Wt = wt + (size_t)2560 * 2048;    N = 512;  int u = id - 5120; bx = u & 15; by = u >> 4; }
  else                { W = Wp; Wt = wt + (size_t)3072 * 2048;    N = 2048; int u = id - 6144; bx = u & 63; by = u >> 6; }
  const int K = 2048;
  bx *= 32; by *= 32;
  int tx = threadIdx.x & 31, ty = threadIdx.x >> 5;  // 32x8
#pragma unroll
  for (int r = 0; r < 32; r += 8)
    tile[ty + r][tx] = W[(size_t)(by + ty + r) * N + bx + tx];
  __syncthreads();
#pragma unroll
  for (int r = 0; r < 32; r += 8)
    Wt[(size_t)(bx + ty + r) * K + by + tx] = f2bf(tile[tx][ty + r]);
}

// ---------------- V slice of qkv -> vt[(b*NKV+kvh)*HD + d][t]  (bf16 transpose)
__global__ void transpose_v_kernel(const unsigned short* __restrict__ qkv,
                                   unsigned short* __restrict__ vt) {
  __shared__ unsigned short tile[32][33];
  int bh = blockIdx.z;                 // b*NKV + kvh
  int b = bh >> 2, kvh = bh & 3;
  int t0 = blockIdx.x * 32, d0 = blockIdx.y * 32;
  int tx = threadIdx.x & 31, ty = threadIdx.x >> 5;
#pragma unroll
  for (int r = 0; r < 32; r += 8)
    tile[ty + r][tx] = qkv[(size_t)(b * T_ + t0 + ty + r) * NQKV_ + 2560 + kvh * HD_ + d0 + tx];
  __syncthreads();
#pragma unroll
  for (int r = 0; r < 32; r += 8)
    vt[(size_t)(bh * HD_ + d0 + ty + r) * T_ + t0 + tx] = tile[tx][ty + r];
}

// ---------------- bf16 GEMM: C(MxN) = A(MxK) * Bt(NxK)^T, 128x128 tile, BK=32.
// Wave w owns a 32-row x 128-col strip (rope pair d,d+64 stays in-lane).
// ROPE: fused RoPE on cols < 2560 (q,k heads; head width 128 == col-block).
template <typename OUT, bool ROPE>
__global__ __launch_bounds__(256) void gemm_bf16(const unsigned short* __restrict__ A,
                                                 const unsigned short* __restrict__ Bt,
                                                 OUT* __restrict__ Cm,
                                                 const float2* __restrict__ rt,
                                                 int M, int N, int K) {
  constexpr int BK = 32;
  __shared__ __align__(16) unsigned short Al[2][128 * BK];
  __shared__ __align__(16) unsigned short Bl[2][128 * BK];
  int tid = threadIdx.x, w = tid >> 6, lane = tid & 63;
  int l15 = lane & 15, l4 = lane >> 4;
  size_t arow0 = (size_t)blockIdx.y * 128;
  size_t brow0 = (size_t)blockIdx.x * 128;

  f32x4 acc[2][8];
#pragma unroll
  for (int mi = 0; mi < 2; ++mi)
#pragma unroll
    for (int ni = 0; ni < 8; ++ni) acc[mi][ni] = (f32x4){0.f, 0.f, 0.f, 0.f};

  auto stage = [&](int buf, int k0) {
#pragma unroll
    for (int i = 0; i < 2; ++i) {                 // A tile: 8KB = 8 wave-insts
      int c = i * 256 + w * 64 + lane;            // chunk 0..511 (16B each)
      const unsigned short* g = A + (arow0 + (c >> 2)) * K + k0 + (c & 3) * 8;
      GLOAD_LDS16(g, &Al[buf][(i * 4 + w) * 512]);
    }
#pragma unroll
    for (int i = 0; i < 2; ++i) {
      int c = i * 256 + w * 64 + lane;
      const unsigned short* g = Bt + (brow0 + (c >> 2)) * K + k0 + (c & 3) * 8;
      GLOAD_LDS16(g, &Bl[buf][(i * 4 + w) * 512]);
    }
  };

  stage(0, 0);
  __syncthreads();
  int NT = K / BK, cur = 0;
  for (int kt = 0; kt < NT; ++kt) {
    if (kt + 1 < NT) stage(cur ^ 1, (kt + 1) * BK);
    const unsigned short* Ab = &Al[cur][0];
    const unsigned short* Bb = &Bl[cur][0];
    bf16x8 af[2], bfr[8];
#pragma unroll
    for (int mi = 0; mi < 2; ++mi)
      af[mi] = *reinterpret_cast<const bf16x8*>(Ab + (w * 32 + mi * 16 + l15) * BK + l4 * 8);
#pragma unroll
    for (int ni = 0; ni < 8; ++ni)
      bfr[ni] = *reinterpret_cast<const bf16x8*>(Bb + (ni * 16 + l15) * BK + l4 * 8);
#pragma unroll
    for (int mi = 0; mi < 2; ++mi)
#pragma unroll
      for (int ni = 0; ni < 8; ++ni)
        acc[mi][ni] = __builtin_amdgcn_mfma_f32_16x16x32_bf16(af[mi], bfr[ni], acc[mi][ni], 0, 0, 0);
    __syncthreads();
    cur ^= 1;
  }

  bool dorope = ROPE && (brow0 < 2560);  // q/k col-blocks only
#pragma unroll
  for (int mi = 0; mi < 2; ++mi)
#pragma unroll
    for (int r = 0; r < 4; ++r) {
      size_t row = arow0 + w * 32 + mi * 16 + l4 * 4 + r;
      if (dorope) {
        int t = (int)(row & (T_ - 1));
#pragma unroll
        for (int ni = 0; ni < 4; ++ni) {
          float2 cs = rt[t * 64 + ni * 16 + l15];
          float a1 = acc[mi][ni][r], a2 = acc[mi][ni + 4][r];
          size_t col = brow0 + ni * 16 + l15;
          Cm[row * N + col]      = f2bf(a1 * cs.x - a2 * cs.y);
          Cm[row * N + col + 64] = f2bf(a2 * cs.x + a1 * cs.y);
        }
      } else {
#pragma unroll
        for (int ni = 0; ni < 8; ++ni) {
          size_t col = brow0 + ni * 16 + l15;
          float v = acc[mi][ni][r];
          if constexpr (sizeof(OUT) == 4) Cm[row * N + col] = v;
          else                            Cm[row * N + col] = f2bf(v);
        }
      }
    }
}

// ---------------- flash attention: QBLK=128 (4 waves x 32 q-rows), KVBLK=64, GQA
// 32x32 swapped QK^T, in-register softmax (exp2 domain), P^T via xor-32
// exchange. R5 sync structure (prefetch-at-top, ONE barrier/iter). Balanced
// 1D grid, swizzled LDS, defer-max, mask only on diagonal tiles, setprio.
__global__ __launch_bounds__(256, 2) void attn_kernel(const unsigned short* __restrict__ qkv,
                                                      const unsigned short* __restrict__ vt,
                                                      unsigned short* __restrict__ att) {
  constexpr int KB = 64;
  __shared__ __align__(16) unsigned short Kl[2][KB * 128];   // [kv][d] 32KB, swizzled
  __shared__ __align__(16) unsigned short Vl[2][128 * KB];   // [d][kv] 32KB, swizzled
  int tid = threadIdx.x, w = tid >> 6, lane = tid & 63;
  int l31 = lane & 31, hi = lane >> 5;
  int h4 = hi * 4;

  // balanced decode: ids k and k+256 get q-tiles summing to 15
  int id = blockIdx.x;
  int u = id & 255, half = id >> 8;
  int bh = u & 31;
  int qh = u >> 5;                       // 0..7
  int qi = half ? (15 - qh) : qh;        // 0..15
  int q0 = qi * 128;
  int b = bh >> 4, hd = bh & 15, kvh = hd >> 2;
  int qr0 = q0 + w * 32;   // this wave's first q row
  int ql = qr0 + l31;      // this lane's q row

  // Q^T B-fragments, pre-scaled by log2(e)/sqrt(HD)  (softmax in exp2 domain)
  bf16x8 qf[8];
  {
    const unsigned short* qb = qkv + (size_t)(b * T_ + ql) * NQKV_ + hd * HD_ + hi * 8;
    const float scale = 0.08838834764831845f * 1.4426950408889634f;
#pragma unroll
    for (int df = 0; df < 8; ++df) {
      bf16x8 t = *reinterpret_cast<const bf16x8*>(qb + df * 16);
#pragma unroll
      for (int j = 0; j < 8; ++j) t[j] = (__bf16)((float)t[j] * scale);
      qf[df] = t;
    }
  }

  f32x16 o[4];  // O^T accumulators: d = dt*32 + (r&3)+8*(r>>2)+h4, col q=l31
#pragma unroll
  for (int dt = 0; dt < 4; ++dt)
#pragma unroll
    for (int r = 0; r < 16; ++r) o[dt][r] = 0.f;
  float mr = -1e30f, lr = 0.f;

  auto stage = [&](int buf, int kv0) {
#pragma unroll
    for (int i = 0; i < 4; ++i) {  // K tile: chunk c ^= (row&7), row = c>>4
      int c = (i * 4 + w) * 64 + lane;
      int g = c ^ ((c >> 4) & 7);
      const unsigned short* src =
          qkv + (size_t)(b * T_ + kv0 + (g >> 4)) * NQKV_ + C_ + kvh * HD_ + (g & 15) * 8;
      GLOAD_LDS16(src, &Kl[buf][(i * 4 + w) * 512]);
    }
#pragma unroll
    for (int i = 0; i < 4; ++i) {  // V^T tile: chunk c ^= (row&7), row = c>>3
      int c = (i * 4 + w) * 64 + lane;
      int g = c ^ ((c >> 3) & 7);
      const unsigned short* src =
          vt + (size_t)((b * NKV_ + kvh) * HD_ + (g >> 3)) * T_ + kv0 + (g & 7) * 8;
      GLOAD_LDS16(src, &Vl[buf][(i * 4 + w) * 512]);
    }
  };

  int nt = q0 / KB + 2;  // causal: tiles up to q0+128
  stage(0, 0);
  __syncthreads();
  int cur = 0;
  for (int kt = 0; kt < nt; ++kt) {
    int kv0 = kt * KB;
    if (kt + 1 < nt) stage(cur ^ 1, kv0 + KB);  // prefetch: lands at the barrier below

    if (kv0 <= qr0 + 31) {  // wave-uniform: skip fully-masked tiles
      // S^T = K Q^T; lane: q=l31, k = t2*32 + (r&3)+8(r>>2)+h4
      f32x16 s[2];
#pragma unroll
      for (int r = 0; r < 16; ++r) { s[0][r] = 0.f; s[1][r] = 0.f; }
      const unsigned short* Kb = &Kl[cur][0];
      __builtin_amdgcn_s_setprio(1);
#pragma unroll
      for (int t2 = 0; t2 < 2; ++t2)
#pragma unroll
        for (int df = 0; df < 8; ++df) {
          bf16x8 kf = *reinterpret_cast<const bf16x8*>(
              Kb + (((t2 * 32 + l31) * 128 + df * 16 + hi * 8) ^ ((l31 & 7) << 3)));
          s[t2] = __builtin_amdgcn_mfma_f32_32x32x16_bf16(kf, qf[df], s[t2], 0, 0, 0);
        }
      __builtin_amdgcn_s_setprio(0);

      // mask only on diagonal tiles (wave-uniform branch), then row-max
      float rm = -1e30f;
      if ((kv0 + KB - 1) > qr0) {
#pragma unroll
        for (int t2 = 0; t2 < 2; ++t2)
#pragma unroll
          for (int r = 0; r < 16; ++r) {
            float sv = s[t2][r];
            int kcol = kv0 + t2 * 32 + (r & 3) + 8 * (r >> 2) + h4;
            if (kcol > ql) sv = -1e30f;
            s[t2][r] = sv;
            rm = fmaxf(rm, sv);
          }
      } else {
#pragma unroll
        for (int t2 = 0; t2 < 2; ++t2)
#pragma unroll
          for (int r = 0; r < 16; ++r) rm = fmaxf(rm, s[t2][r]);
      }
      rm = fmaxf(rm, __shfl_xor(rm, 32));

      // defer-max (THR = 11 in log2 units -> P bounded by 2^11)
      if (!__all(rm <= mr + 11.0f)) {
        float mnew = fmaxf(mr, rm);
        float alpha = exp2f(mr - mnew);
        mr = mnew;
        lr *= alpha;
#pragma unroll
        for (int dt = 0; dt < 4; ++dt)
#pragma unroll
          for (int r = 0; r < 16; ++r) o[dt][r] *= alpha;
      }

      // exp2 + per-lane partial sum (cross-half reduce deferred to epilogue)
      float ps = 0.f;
#pragma unroll
      for (int t2 = 0; t2 < 2; ++t2)
#pragma unroll
        for (int r = 0; r < 16; ++r) {
          float p = exp2f(s[t2][r] - mr);
          s[t2][r] = p;
          ps += p;
        }
      lr += ps;

      // pack P to bf16 pairs
      unsigned pk[2][8];
#pragma unroll
      for (int t2 = 0; t2 < 2; ++t2)
#pragma unroll
        for (int i = 0; i < 8; ++i) {
          union { unsigned u32; __bf16 hh[2]; } pr;
          pr.hh[0] = (__bf16)s[t2][2 * i];
          pr.hh[1] = (__bf16)s[t2][2 * i + 1];
          pk[t2][i] = pr.u32;
        }

      // assemble P^T B-frags via xor-32 exchange
      bf16x8 pb[4];
#pragma unroll
      for (int f = 0; f < 4; ++f) {
        int t2 = f >> 1, bq = (f & 1) * 4;
        union { bf16x8 v; unsigned d[4]; } fr;
#pragma unroll
        for (int p = 0; p < 2; ++p) {
          unsigned uu = pk[t2][bq + p];          // consumed by hi=0 lanes
          unsigned ww = pk[t2][bq + 2 + p];      // consumed by hi=1 lanes
          unsigned us = (unsigned)__shfl_xor((int)uu, 32);
          unsigned ws = (unsigned)__shfl_xor((int)ww, 32);
          fr.d[p]     = hi ? ws : uu;
          fr.d[2 + p] = hi ? ww : us;
        }
        pb[f] = fr.v;
      }

      // O^T += V^T P^T
      const unsigned short* Vb = &Vl[cur][0];
      __builtin_amdgcn_s_setprio(1);
#pragma unroll
      for (int dt = 0; dt < 4; ++dt)
#pragma unroll
        for (int kf = 0; kf < 4; ++kf) {
          bf16x8 vf = *reinterpret_cast<const bf16x8*>(
              Vb + (((dt * 32 + l31) * KB + kf * 16 + hi * 8) ^ ((l31 & 7) << 3)));
          o[dt] = __builtin_amdgcn_mfma_f32_32x32x16_bf16(vf, pb[kf], o[dt], 0, 0, 0);
        }
      __builtin_amdgcn_s_setprio(0);
    }

    __syncthreads();  // drains prefetch + guards buffer reuse
    cur ^= 1;
  }

  // epilogue: finish l reduce, normalize, scatter O^T back to att[q][d]
  float ls = lr + __shfl_xor(lr, 32);
  float inv = 1.f / ls;
  unsigned short* ob = att + (size_t)(b * T_ + ql) * C_ + hd * HD_;
#pragma unroll
  for (int dt = 0; dt < 4; ++dt)
#pragma unroll
    for (int r = 0; r < 16; ++r) {
      int d = dt * 32 + (r & 3) + 8 * (r >> 2) + h4;
      ob[d] = f2bf(o[dt][r] * inv);
    }
}

extern "C" void kernel_launch(void* const* d_in, const int* in_sizes, int n_in,
                              void* d_out, int out_size, void* d_ws, size_t ws_size,
                              hipStream_t stream) {
  const float* x  = (const float*)d_in[0];
  const float* Wq = (const float*)d_in[1];
  const float* Wk = (const float*)d_in[2];
  const float* Wv = (const float*)d_in[3];
  const float* Wp = (const float*)d_in[4];
  float* out = (float*)d_out;
  char* ws = (char*)d_ws;

  // workspace layout (bytes); total 68,157,440
  unsigned short* xb  = (unsigned short*)(ws);              // 4096x2048 bf16 (reused as att)
  unsigned short* wt  = (unsigned short*)(ws + 16777216);   // 5120x2048 bf16 (Wq^T|Wk^T|Wv^T|Wp^T)
  unsigned short* qkv = (unsigned short*)(ws + 37748736);   // 4096x3072 bf16
  float2*         rt  = (float2*)(ws + 62914560);           // 2048x64 {cos,sin}
  unsigned short* vt  = (unsigned short*)(ws + 63963136);   // 8x128x2048 bf16
  unsigned short* att = xb;                                 // alias: xb dead after GEMM1

  rope_table_kernel<<<T_, 64, 0, stream>>>(rt);
  convx_kernel<<<(M_ * C_ / 4 + 255) / 256, 256, 0, stream>>>(x, xb, M_ * C_ / 4);
  transpose_conv4_kernel<<<dim3(10240), 256, 0, stream>>>(Wq, Wk, Wv, Wp, wt);

  gemm_bf16<unsigned short, true><<<dim3(NQKV_ / 128, M_ / 128), 256, 0, stream>>>(
      xb, wt, qkv, rt, M_, NQKV_, C_);
  transpose_v_kernel<<<dim3(T_ / 32, HD_ / 32, B_ * NKV_), 256, 0, stream>>>(qkv, vt);
  attn_kernel<<<dim3(512), 256, 0, stream>>>(qkv, vt, att);
  gemm_bf16<float, false><<<dim3(C_ / 128, M_ / 128), 256, 0, stream>>>(
      att, wt + (size_t)3072 * 2048, out, nullptr, M_, C_, C_);
}